// Round 6
// baseline (333.401 us; speedup 1.0000x reference)
//
#include <hip/hip_runtime.h>
#include <hip/hip_bf16.h>

#define B_ 32
#define S_ 2048
#define D_ 512
#define M_ (B_*S_)   // 65536 rows

typedef __bf16 bf16x8 __attribute__((ext_vector_type(8)));
typedef float  f32x4  __attribute__((ext_vector_type(4)));
typedef unsigned int u32x4 __attribute__((ext_vector_type(4)));

__device__ __forceinline__ float tanh_fast(float x){
  float e2 = __expf(2.f * x);                    // inf for large x -> rcp=0 -> 1
  return 1.f - 2.f * __builtin_amdgcn_rcpf(e2 + 1.f);
}

__device__ __forceinline__ bf16x8 cvt8(f32x4 a, f32x4 b){
  bf16x8 t;
  t[0]=(__bf16)a[0]; t[1]=(__bf16)a[1]; t[2]=(__bf16)a[2]; t[3]=(__bf16)a[3];
  t[4]=(__bf16)b[0]; t[5]=(__bf16)b[1]; t[6]=(__bf16)b[2]; t[7]=(__bf16)b[3];
  return t;
}

// non-temporal 16B load (bypass L1 -> keep L1 for A reuse within block)
__device__ __forceinline__ bf16x8 ldB(const unsigned short* p){
  u32x4 u = __builtin_nontemporal_load((const u32x4*)p);
  return __builtin_bit_cast(bf16x8, u);
}

// ---- fused prelude: blocks [0,128) reorder w_v into MFMA B-frag order;
//      blocks [128,256) compute qproj[b,d] = q[b]@wq[:,d]+bias[d].
__global__ void k_prelude(const float* __restrict__ wv,
                          unsigned short* __restrict__ wvr,
                          const float* __restrict__ q,
                          const float* __restrict__ wq,
                          const float* __restrict__ bias,
                          float* __restrict__ qp){
  __shared__ float qs[D_];
  __shared__ float red[2][128];
  int t = threadIdx.x;                  // 256
  if (blockIdx.x < 128){
    // frag f = ks*32 + nt. lane holds B[k=ks*32+quad*8+j][n=nt*16+lm], j=0..7
    int frag = blockIdx.x*4 + (t>>6);   // 0..511
    int lane = t & 63;
    int ks = frag >> 5, nt = frag & 31;
    int k0 = ks*32 + ((lane>>4)&3)*8;
    int d  = nt*16 + (lane&15);
    bf16x8 v;
    #pragma unroll
    for (int j=0;j<8;++j) v[j] = (__bf16)wv[(k0+j)*D_ + d];
    *reinterpret_cast<uint4*>(wvr + ((size_t)frag*64 + lane)*8) =
        __builtin_bit_cast(uint4, v);
  } else {
    int j  = blockIdx.x - 128;          // 0..127
    int b  = j >> 2, dg = j & 3;        // 4 d-groups x 128 cols
    int dl = t & 127, eg = t >> 7;      // 2-way k-split
    int d  = dg*128 + dl;
    for (int e=t; e<D_; e+=256) qs[e] = q[b*D_+e];
    __syncthreads();
    float acc = 0.f;
    #pragma unroll 8
    for (int i=0;i<256;++i){
      int e = eg*256 + i;
      acc = fmaf(qs[e], wq[(size_t)e*D_+d], acc);
    }
    red[eg][dl] = acc;
    __syncthreads();
    if (eg == 0)
      qp[b*D_+d] = red[0][dl] + red[1][dl] + bias[d];
  }
}

// ---- fused (value@w_v + qproj + loc) -> tanh -> dot(score_w) -> scores ----
// Block: 64 rows x 512 cols, 4 waves (one per 128-col group, same rows).
// Barrier-free kc loop, FULL-ITERATION register double-buffer for B (bC/bN)
// and A (aN), mt-outer MFMA order (only af[4] cvt regs live). B loads are
// non-temporal; kc order phase-staggered per block to spread L2 pressure.
__launch_bounds__(256, 2)
__global__ void k_energy(const float* __restrict__ value,
                         const unsigned short* __restrict__ wvr,
                         const float* __restrict__ qp,
                         const float* __restrict__ energy,
                         const float* __restrict__ conv_w,
                         const float* __restrict__ conv_b,
                         const float* __restrict__ score_w,
                         float* __restrict__ scores){
  const int t    = threadIdx.x;
  const int wave = t >> 6;
  const int lane = t & 63;
  const int quad = lane >> 4;
  const int lm   = lane & 15;
  const int row0 = blockIdx.x * 64;
  const int b    = row0 >> 11;          // 64 | 2048 -> one batch per block
  const int s0   = row0 & (S_-1);
  const int phase = blockIdx.x & 15;

  f32x4 acc[4][8];
  #pragma unroll
  for (int mt=0;mt<4;++mt)
    #pragma unroll
    for (int nt=0;nt<8;++nt)
      acc[mt][nt] = (f32x4){0.f,0.f,0.f,0.f};

  // A: lane holds A[m=lm][k=quad*8+j] for row-tile mt (rows row0+mt*16+lm)
  const float* aP = value + (size_t)(row0+lm)*D_ + quad*8;
  // B: frag f = kc*32 + wave*8 + nt
  const unsigned short* bP = wvr + ((size_t)(wave*8)*64 + lane)*8;

  f32x4  aN[4][2];
  bf16x8 bC[8], bN[8];
  {
    const int k0 = phase;
    #pragma unroll
    for (int mt=0;mt<4;++mt){
      const float* p = aP + (size_t)mt*16*D_ + k0*32;
      aN[mt][0] = *reinterpret_cast<const f32x4*>(p);
      aN[mt][1] = *reinterpret_cast<const f32x4*>(p+4);
    }
    #pragma unroll
    for (int nt=0;nt<8;++nt)
      bC[nt] = ldB(bP + (size_t)(k0*32+nt)*512);
  }

  #pragma unroll
  for (int u=0; u<16; ++u){
    const int kn = (u + 1 + phase) & 15;
    bf16x8 af[4];
    #pragma unroll
    for (int mt=0;mt<4;++mt) af[mt] = cvt8(aN[mt][0], aN[mt][1]);
    if (u < 15){
      #pragma unroll
      for (int mt=0;mt<4;++mt){
        const float* p = aP + (size_t)mt*16*D_ + kn*32;
        aN[mt][0] = *reinterpret_cast<const f32x4*>(p);
        aN[mt][1] = *reinterpret_cast<const f32x4*>(p+4);
      }
      #pragma unroll
      for (int nt=0;nt<8;++nt)
        bN[nt] = ldB(bP + (size_t)(kn*32+nt)*512);
    }
    #pragma unroll
    for (int mt=0;mt<4;++mt)
      #pragma unroll
      for (int nt=0;nt<8;++nt)
        acc[mt][nt] = __builtin_amdgcn_mfma_f32_16x16x32_bf16(af[mt], bC[nt], acc[mt][nt], 0,0,0);
    if (u < 15){
      #pragma unroll
      for (int nt=0;nt<8;++nt) bC[nt] = bN[nt];
    }
  }

  // epilogue: per-lane d = wave*128 + nt*16 + lm
  float sw[8], c0[8], c1[8], c2[8], cb[8], qv[8];
  #pragma unroll
  for (int nt=0; nt<8; ++nt){
    int d = wave*128 + nt*16 + lm;
    sw[nt] = score_w[d];
    c0[nt] = conv_w[d*3+0];
    c1[nt] = conv_w[d*3+1];
    c2[nt] = conv_w[d*3+2];
    cb[nt] = conv_b[d];
    qv[nt] = qp[b*D_+d];
  }
  __shared__ float red[4][64];
  const float* eB = energy + b*S_;
  #pragma unroll
  for (int mt=0; mt<4; ++mt){
    #pragma unroll
    for (int r=0;r<4;++r){
      int sl = mt*16 + quad*4 + r;              // C/D layout: row=quad*4+reg
      int s  = s0 + sl;
      float em1 = (s > 0)    ? eB[s-1] : 0.f;
      float e0  =              eB[s];
      float ep1 = (s < S_-1) ? eB[s+1] : 0.f;
      float p = 0.f;
      #pragma unroll
      for (int nt=0; nt<8; ++nt){
        float h = acc[mt][nt][r] + qv[nt]
                + fmaf(c0[nt],em1, fmaf(c1[nt],e0, fmaf(c2[nt],ep1, cb[nt])));
        p = fmaf(sw[nt], tanh_fast(h), p);
      }
      #pragma unroll
      for (int m=1; m<16; m<<=1) p += __shfl_xor(p, m, 64);   // reduce 16 cols
      if (lm == 0) red[wave][sl] = p;
    }
  }
  __syncthreads();
  if (t < 64)
    scores[row0 + t] = red[0][t] + red[1][t] + red[2][t] + red[3][t];
}

// ---- fused softmax + context + reduce. Block (sc,b): 64 s-rows. Recomputes
// block-wide max/sum over scores[b,:] (8 KB, L2-hot; score_b cancels in
// softmax), writes align slice, atomically accumulates context into d_out
// (zeroed via hipMemsetAsync before this kernel).
__launch_bounds__(256)
__global__ void k_ctx(const float* __restrict__ scores,
                      const float* __restrict__ value,
                      float* __restrict__ out_align,
                      float* __restrict__ out_ctx){
  int b = blockIdx.y, sc = blockIdx.x;   // sc: 0..31
  int t = threadIdx.x;                   // 256
  int lane = t & 63, wid = t >> 6;       // 4 waves
  __shared__ float redm[4], reds[4];
  __shared__ float als[64];
  __shared__ float lred[4][D_];          // 8 KB

  float v[8], mx = -3.4e38f;
  #pragma unroll
  for (int i=0;i<8;++i){
    v[i] = scores[b*S_ + t + i*256];
    mx = fmaxf(mx, v[i]);
  }
  #pragma unroll
  for (int m=1;m<64;m<<=1) mx = fmaxf(mx, __shfl_xor(mx, m, 64));
  if (lane==0) redm[wid] = mx;
  __syncthreads();
  mx = fmaxf(fmaxf(redm[0],redm[1]), fmaxf(redm[2],redm[3]));
  float sum = 0.f;
  #pragma unroll
  for (int i=0;i<8;++i) sum += __expf(v[i]-mx);
  #pragma unroll
  for (int m=1;m<64;m<<=1) sum += __shfl_xor(sum, m, 64);
  if (lane==0) reds[wid] = sum;
  __syncthreads();
  sum = reds[0]+reds[1]+reds[2]+reds[3];
  float inv = 1.f/sum;

  if (t < 64){
    float a = __expf(scores[b*S_ + sc*64 + t] - mx) * inv;
    out_align[b*S_ + sc*64 + t] = a;
    als[t] = a;
  }
  __syncthreads();

  int r = t >> 6;            // 0..3 (s subgroup)
  int c = (t & 63) * 8;      // 8 d per thread (two 16B loads)
  f32x4 a0 = (f32x4){0.f,0.f,0.f,0.f};
  f32x4 a1 = (f32x4){0.f,0.f,0.f,0.f};
  #pragma unroll 4
  for (int i=0;i<16;++i){
    int sl = i*4 + r;
    float al = als[sl];
    const float* vp = value + ((size_t)(b*S_ + sc*64 + sl))*D_ + c;
    a0 += al * *reinterpret_cast<const f32x4*>(vp);
    a1 += al * *reinterpret_cast<const f32x4*>(vp+4);
  }
  #pragma unroll
  for (int j=0;j<4;++j){ lred[r][c+j] = a0[j]; lred[r][c+4+j] = a1[j]; }
  __syncthreads();
  if (r == 0){
    #pragma unroll
    for (int j=0;j<8;++j)
      atomicAdd(&out_ctx[b*D_ + c + j],
                lred[0][c+j] + lred[1][c+j] + lred[2][c+j] + lred[3][c+j]);
  }
}

extern "C" void kernel_launch(void* const* d_in, const int* in_sizes, int n_in,
                              void* d_out, int out_size, void* d_ws, size_t ws_size,
                              hipStream_t stream){
  const float* query   = (const float*)d_in[0];
  const float* value   = (const float*)d_in[1];
  const float* energy  = (const float*)d_in[2];
  const float* conv_w  = (const float*)d_in[3];
  const float* conv_b  = (const float*)d_in[4];
  const float* w_q     = (const float*)d_in[5];
  const float* w_v     = (const float*)d_in[6];
  const float* bias    = (const float*)d_in[7];
  const float* score_w = (const float*)d_in[8];
  // score_b (d_in[9]) cancels in softmax -> unused.

  char* ws = (char*)d_ws;
  unsigned short* wvr = (unsigned short*)(ws);            // 512 KB (bf16 frags)
  float* qp     = (float*)(ws + (512<<10));               // 64 KB
  float* scores = (float*)(ws + (576<<10));               // 256 KB (65536 f32)

  float* out_ctx   = (float*)d_out;                       // [B, D] fp32
  float* out_align = out_ctx + B_*D_;                     // [B, S] fp32

  hipMemsetAsync(out_ctx, 0, (size_t)B_*D_*sizeof(float), stream);
  k_prelude<<<dim3(256),     dim3(256), 0, stream>>>(w_v, wvr, query, w_q, bias, qp);
  k_energy <<<dim3(M_/64),   dim3(256), 0, stream>>>(value, wvr, qp, energy,
                                                     conv_w, conv_b, score_w, scores);
  k_ctx    <<<dim3(32,B_),   dim3(256), 0, stream>>>(scores, value, out_align, out_ctx);
}

// Round 7
// 304.728 us; speedup vs baseline: 1.0941x; 1.0941x over previous
//
#include <hip/hip_runtime.h>
#include <hip/hip_bf16.h>

#define B_ 32
#define S_ 2048
#define D_ 512
#define M_ (B_*S_)   // 65536 rows
#define KS_ 16       // K steps of 32 (512/32)

typedef __bf16 bf16x8 __attribute__((ext_vector_type(8)));
typedef float  f32x4  __attribute__((ext_vector_type(4)));

__device__ __forceinline__ float tanh_fast(float x){
  float e2 = __expf(2.f * x);                    // inf for large x -> rcp=0 -> 1
  return 1.f - 2.f * __builtin_amdgcn_rcpf(e2 + 1.f);
}
__device__ __forceinline__ float b2f(unsigned short u){
  unsigned int x = ((unsigned int)u) << 16;
  return __builtin_bit_cast(float, x);
}
__device__ __forceinline__ bf16x8 cvt8(f32x4 a, f32x4 b){
  bf16x8 t;
  t[0]=(__bf16)a[0]; t[1]=(__bf16)a[1]; t[2]=(__bf16)a[2]; t[3]=(__bf16)a[3];
  t[4]=(__bf16)b[0]; t[5]=(__bf16)b[1]; t[6]=(__bf16)b[2]; t[7]=(__bf16)b[3];
  return t;
}
__device__ __forceinline__ void gl_lds16(const void* g, void* l){
  __builtin_amdgcn_global_load_lds(
      (const __attribute__((address_space(1))) unsigned int*)g,
      (__attribute__((address_space(3))) unsigned int*)l, 16, 0, 0);
}

// ---- fused prelude ----
// blocks [0,4096):    value fp32 -> bf16 copy (valueb)
// blocks [4096,4224): reorder w_v into wvr2[ks][nh][ntl][lane][8] frag slabs
// blocks [4224,4352): qproj[b,d] = q[b]@wq[:,d] + bias[d]
__global__ void k_prep(const float* __restrict__ value, unsigned short* __restrict__ valueb,
                       const float* __restrict__ wv, unsigned short* __restrict__ wvr2,
                       const float* __restrict__ q, const float* __restrict__ wq,
                       const float* __restrict__ bias, float* __restrict__ qp){
  __shared__ float qs[D_];
  __shared__ float red[2][128];
  const int bi = blockIdx.x, t = threadIdx.x;
  if (bi < 4096){
    size_t base = (size_t)bi * 8192;
    #pragma unroll
    for (int i=0;i<4;++i){
      size_t idx = base + (size_t)(i*256 + t)*8;
      f32x4 a = *reinterpret_cast<const f32x4*>(value + idx);
      f32x4 b = *reinterpret_cast<const f32x4*>(value + idx + 4);
      *reinterpret_cast<uint4*>(valueb + idx) = __builtin_bit_cast(uint4, cvt8(a,b));
    }
  } else if (bi < 4224){
    int g = (bi-4096)*256 + t;       // 0..32767 = 512 frags x 64 lanes
    int lane = g & 63, frag = g >> 6;
    int ntl = frag & 7, nh = (frag>>3)&3, ks = frag>>5;
    int nt = nh*8 + ntl;
    int k0 = ks*32 + (lane>>4)*8;    // quad*8
    int d  = nt*16 + (lane&15);
    bf16x8 v;
    #pragma unroll
    for (int j=0;j<8;++j) v[j] = (__bf16)wv[(size_t)(k0+j)*D_ + d];
    *reinterpret_cast<uint4*>(wvr2 + ((size_t)frag*64 + lane)*8) =
        __builtin_bit_cast(uint4, v);
  } else {
    int j  = bi - 4224;              // 0..127
    int b  = j >> 2, dg = j & 3;
    int dl = t & 127, eg = t >> 7;   // 2-way k-split
    int d  = dg*128 + dl;
    for (int e=t; e<D_; e+=256) qs[e] = q[b*D_+e];
    __syncthreads();
    float acc = 0.f;
    #pragma unroll 8
    for (int i=0;i<256;++i){
      int e = eg*256 + i;
      acc = fmaf(qs[e], wq[(size_t)e*D_+d], acc);
    }
    red[eg][dl] = acc;
    __syncthreads();
    if (eg == 0)
      qp[b*D_+d] = red[0][dl] + red[1][dl] + bias[d];
  }
}

// ---- m97-form GEMM + epilogue: hidden=tanh(Av@Wv + qp + loc), p=hidden@sw ----
// 2048 blocks = 512 row-tiles(128) x 4 col-slabs(128). 4 waves: wh=row half,
// wc=col half; per wave 4mt x 4nt of 16x16x32 bf16 MFMA (64 AGPR acc).
// Both A and B staged via global_load_lds (16B), double-buffered, BK=32.
// A LDS uses XOR chunk swizzle (applied on DMA *source* addr) for ds_read.
__launch_bounds__(256)
__global__ void k_energy(const unsigned short* __restrict__ valueb,
                         const unsigned short* __restrict__ wvr2,
                         const float* __restrict__ qp,
                         const float* __restrict__ energy,
                         const float* __restrict__ conv_w,
                         const float* __restrict__ conv_b,
                         const float* __restrict__ score_w,
                         float* __restrict__ sp){
  __shared__ __align__(16) unsigned short As[2][4096];   // 8 KB per buf
  __shared__ __align__(16) unsigned short Bs[2][4096];
  __shared__ float red[2][128];

  const int t    = threadIdx.x;
  const int wave = t >> 6;
  const int lane = t & 63;
  const int quad = lane >> 4;
  const int lm   = lane & 15;
  const int wh   = wave & 1;
  const int wc   = wave >> 1;
  const int rt   = blockIdx.x >> 2;
  const int nh   = blockIdx.x & 3;
  const int row0 = rt * 128;
  const int b    = row0 >> 11;       // 128 | 2048
  const int s0   = row0 & (S_-1);

  // A DMA source: unit u = j*256+t -> row=j*64+(t>>2), chunk gc=(t&3)^((t>>2)&3)
  const unsigned short* gA0 = valueb + (size_t)(row0 + (t>>2))*D_
                                     + ((t&3) ^ ((t>>2)&3))*8;
  const unsigned short* gA1 = gA0 + (size_t)64*D_;
  // B DMA source: per step (ks*4+nh)*4096 elems; unit u -> +u*8
  const unsigned short* gB  = wvr2 + (size_t)nh*4096 + t*8;

  f32x4 acc[4][4];
  #pragma unroll
  for (int mt=0;mt<4;++mt)
    #pragma unroll
    for (int nt=0;nt<4;++nt)
      acc[mt][nt] = (f32x4){0.f,0.f,0.f,0.f};

  // prologue: stage ks=0 into buf 0
  gl_lds16(gA0, &As[0][t*8]);
  gl_lds16(gA1, &As[0][2048 + t*8]);
  gl_lds16(gB,        &Bs[0][t*8]);
  gl_lds16(gB + 2048, &Bs[0][2048 + t*8]);
  __syncthreads();

  for (int ks=0; ks<KS_; ++ks){
    const int buf = ks & 1;
    if (ks < KS_-1){
      gl_lds16(gA0 + (ks+1)*32, &As[buf^1][t*8]);
      gl_lds16(gA1 + (ks+1)*32, &As[buf^1][2048 + t*8]);
      gl_lds16(gB + (ks+1)*16384,        &Bs[buf^1][t*8]);
      gl_lds16(gB + (ks+1)*16384 + 2048, &Bs[buf^1][2048 + t*8]);
    }
    const unsigned short* Ab = &As[buf][0];
    const unsigned short* Bb = &Bs[buf][0];
    bf16x8 a[4], bf[4];
    #pragma unroll
    for (int mt=0;mt<4;++mt){
      int arow = wh*64 + mt*16 + lm;
      a[mt] = *reinterpret_cast<const bf16x8*>(
                &Ab[arow*32 + ((quad ^ (lm&3)))*8]);
    }
    #pragma unroll
    for (int nt=0;nt<4;++nt)
      bf[nt] = *reinterpret_cast<const bf16x8*>(
                &Bb[((wc*4+nt)*64 + lane)*8]);
    #pragma unroll
    for (int mt=0;mt<4;++mt)
      #pragma unroll
      for (int nt=0;nt<4;++nt)
        acc[mt][nt] = __builtin_amdgcn_mfma_f32_16x16x32_bf16(a[mt], bf[nt], acc[mt][nt], 0,0,0);
    __syncthreads();
  }

  // epilogue: per-lane d = nh*128 + wc*64 + nt*16 + lm
  float sw[4], c0[4], c1[4], c2[4], cb[4], qv[4];
  #pragma unroll
  for (int nt=0; nt<4; ++nt){
    int d = nh*128 + wc*64 + nt*16 + lm;
    sw[nt] = score_w[d];
    c0[nt] = conv_w[d*3+0];
    c1[nt] = conv_w[d*3+1];
    c2[nt] = conv_w[d*3+2];
    cb[nt] = conv_b[d];
    qv[nt] = qp[b*D_+d];
  }
  const float* eB = energy + b*S_;
  #pragma unroll
  for (int mt=0; mt<4; ++mt){
    #pragma unroll
    for (int r=0;r<4;++r){
      int sl = wh*64 + mt*16 + quad*4 + r;      // C/D layout: row=quad*4+reg
      int s  = s0 + sl;
      float em1 = (s > 0)    ? eB[s-1] : 0.f;
      float e0  =              eB[s];
      float ep1 = (s < S_-1) ? eB[s+1] : 0.f;
      float p = 0.f;
      #pragma unroll
      for (int nt=0; nt<4; ++nt){
        float h = acc[mt][nt][r] + qv[nt]
                + fmaf(c0[nt],em1, fmaf(c1[nt],e0, fmaf(c2[nt],ep1, cb[nt])));
        p = fmaf(sw[nt], tanh_fast(h), p);
      }
      #pragma unroll
      for (int m=1; m<16; m<<=1) p += __shfl_xor(p, m, 64);   // reduce 16 cols
      if (lm == 0) red[wc][sl] = p;
    }
  }
  __syncthreads();
  if (t < 128)
    sp[(size_t)nh*M_ + row0 + t] = red[0][t] + red[1][t];
}

// ---- softmax over S per batch (sums 4 col-slab partials); score_b cancels ----
__global__ void k_softmax(const float* __restrict__ sp,
                          float* __restrict__ out_align){
  int b = blockIdx.x, t = threadIdx.x;
  int lane = t & 63, wid = t >> 6;
  float v[8], mx = -3.4e38f;
  #pragma unroll
  for (int i=0;i<8;++i){
    int s = t + i*256;
    float sc = sp[0*M_+b*S_+s] + sp[1*M_+b*S_+s] + sp[2*M_+b*S_+s] + sp[3*M_+b*S_+s];
    v[i] = sc;
    mx = fmaxf(mx, sc);
  }
  __shared__ float red[4], red2[4];
  #pragma unroll
  for (int m=1;m<64;m<<=1) mx = fmaxf(mx, __shfl_xor(mx, m, 64));
  if (lane==0) red[wid] = mx;
  __syncthreads();
  mx = fmaxf(fmaxf(red[0],red[1]), fmaxf(red[2],red[3]));
  float sum = 0.f;
  #pragma unroll
  for (int i=0;i<8;++i){ v[i] = __expf(v[i]-mx); sum += v[i]; }
  #pragma unroll
  for (int m=1;m<64;m<<=1) sum += __shfl_xor(sum, m, 64);
  if (lane==0) red2[wid] = sum;
  __syncthreads();
  sum = red2[0]+red2[1]+red2[2]+red2[3];
  float inv = 1.f/sum;
  #pragma unroll
  for (int i=0;i<8;++i) out_align[b*S_ + t + i*256] = v[i]*inv;
}

// ---- context partials from bf16 value copy: block (sc,b) = 128 s-rows ----
__launch_bounds__(512)
__global__ void k_ctx(const unsigned short* __restrict__ valueb,
                      const float* __restrict__ align,
                      float* __restrict__ cpart){
  int b = blockIdx.y, sc = blockIdx.x;   // sc: 0..15
  int t = threadIdx.x;                   // 512
  int r = t >> 6;            // 0..7 (s subgroup)
  int c = (t & 63) * 8;      // 8 d per thread (one 16B bf16 load)
  __shared__ float als[128];
  __shared__ float lred[8][D_];          // 16 KB
  if (t < 128) als[t] = align[b*S_ + sc*128 + t];
  __syncthreads();
  float acc[8] = {0,0,0,0,0,0,0,0};
  #pragma unroll 4
  for (int i=0;i<16;++i){
    int sl = i*8 + r;
    float al = als[sl];
    uint4 u = *reinterpret_cast<const uint4*>(
                valueb + ((size_t)(b*S_ + sc*128 + sl))*D_ + c);
    unsigned short tt[8]; __builtin_memcpy(tt, &u, 16);
    #pragma unroll
    for (int j=0;j<8;++j) acc[j] = fmaf(al, b2f(tt[j]), acc[j]);
  }
  #pragma unroll
  for (int j=0;j<8;++j) lred[r][c+j] = acc[j];
  __syncthreads();
  if (r == 0){
    #pragma unroll
    for (int j=0;j<8;++j){
      float s = 0.f;
      #pragma unroll
      for (int k=0;k<8;++k) s += lred[k][c+j];
      cpart[((size_t)(b*16+sc))*D_ + c + j] = s;
    }
  }
}

__global__ void k_ctx_reduce(const float* __restrict__ cpart,
                             float* __restrict__ out_ctx){
  int idx = blockIdx.x*256 + threadIdx.x;   // 0..16383
  int b = idx >> 9, d = idx & 511;
  float s = 0.f;
  #pragma unroll
  for (int j=0;j<16;++j) s += cpart[((size_t)(b*16+j))*D_ + d];
  out_ctx[idx] = s;
}

extern "C" void kernel_launch(void* const* d_in, const int* in_sizes, int n_in,
                              void* d_out, int out_size, void* d_ws, size_t ws_size,
                              hipStream_t stream){
  const float* query   = (const float*)d_in[0];
  const float* value   = (const float*)d_in[1];
  const float* energy  = (const float*)d_in[2];
  const float* conv_w  = (const float*)d_in[3];
  const float* conv_b  = (const float*)d_in[4];
  const float* w_q     = (const float*)d_in[5];
  const float* w_v     = (const float*)d_in[6];
  const float* bias    = (const float*)d_in[7];
  const float* score_w = (const float*)d_in[8];
  // score_b (d_in[9]) cancels in softmax -> unused.

  char* ws = (char*)d_ws;
  unsigned short* valueb = (unsigned short*)(ws);         // 64 MB (33.55M bf16)
  unsigned short* wvr2   = (unsigned short*)(ws + ((size_t)65536<<10)); // 512 KB
  float* qp     = (float*)(ws + ((size_t)66048<<10));     // 64 KB
  float* sp     = (float*)(ws + ((size_t)66112<<10));     // 1 MB (4 x 65536)
  float* cpart  = (float*)(ws + ((size_t)67136<<10));     // 1 MB (32*16 x 512)
  // total ~68.2 MB

  float* out_ctx   = (float*)d_out;                       // [B, D] fp32
  float* out_align = out_ctx + B_*D_;                     // [B, S] fp32

  k_prep      <<<dim3(4352),      dim3(256), 0, stream>>>(value, valueb, w_v, wvr2,
                                                          query, w_q, bias, qp);
  k_energy    <<<dim3(2048),      dim3(256), 0, stream>>>(valueb, wvr2, qp, energy,
                                                          conv_w, conv_b, score_w, sp);
  k_softmax   <<<dim3(B_),        dim3(256), 0, stream>>>(sp, out_align);
  k_ctx       <<<dim3(16,B_),     dim3(512), 0, stream>>>(valueb, out_align, cpart);
  k_ctx_reduce<<<dim3(B_*D_/256), dim3(256), 0, stream>>>(cpart, out_ctx);
}